// Round 14
// baseline (240.195 us; speedup 1.0000x reference)
//
#include <hip/hip_runtime.h>
#include <hip/hip_bf16.h>

typedef short short8 __attribute__((ext_vector_type(8)));
typedef float floatx4 __attribute__((ext_vector_type(4)));
typedef unsigned short ushort;

#define Bb 128
#define Nn 256
#define Hh 150
#define HK 160        // padded col dim for h,c storage
#define Vv 32000
#define NROW 384      // 3 trees * B
#define PROJC 600
#define NINT 64       // internal nodes per tree (0..63)
#define ZROW (Vv + NROW * NINT)   // 56576: zero sentinel row (fits ushort)

#define WTN 640       // Wt padded col count (40 tiles of 16)

// Wt/proj COLUMN LAYOUT (gate-interleaved): col c = k*4 + g,
// g: 0=i, 1=o, 2=u, 3=f; k = 0..149 real, 150..159 zero pad.
// -> proj row holds {i,o,u,f} of output-k contiguously: one short4 at 4k.

__device__ __forceinline__ float sigf(float x) { return 1.0f / (1.0f + __expf(-x)); }
__device__ __forceinline__ float tanhf_(float x) { return 1.0f - 2.0f / (__expf(2.0f * x) + 1.0f); }
__device__ __forceinline__ float bf2f(ushort s) { union { float f; unsigned u; } v; v.u = ((unsigned)s) << 16; return v.f; }
__device__ __forceinline__ ushort f2bf(float f) { __hip_bfloat16 h = __float2bfloat16(f); return *(ushort*)&h; }

// ---------------- prep: weights -> bf16 B-operand layout + zero sentinel ----
// WRITE-contiguous orientation (r13 measured-best).
__global__ __launch_bounds__(256) void k_prep(
    const float* __restrict__ W_iou, const float* __restrict__ W_f,
    const float* __restrict__ U_iou, const float* __restrict__ U_f,
    const float* __restrict__ b_iou, const float* __restrict__ b_f,
    short* __restrict__ Wt, short* __restrict__ Uti, short* __restrict__ Utf,
    float* __restrict__ biasw, ushort* __restrict__ h_u, float* __restrict__ c_u)
{
    int idx = blockIdx.x * 256 + threadIdx.x;
    const int nWt = WTN * 320, nUi = 464 * 160, nUf = 160 * 160;
    if (idx < nWt) {
        int c = idx / 320, kk = idx % 320;   // c = out col (gate-interleaved), kk = E index
        int k = c >> 2, g = c & 3;
        float v = 0.f;
        if (kk < 300 && k < 150)
            v = (g < 3) ? W_iou[kk * 450 + g * 150 + k] : W_f[kk * 150 + k];
        Wt[idx] = (short)f2bf(v);
    } else if (idx < nWt + nUi) {
        int i2 = idx - nWt; int n = i2 / 160, k = i2 % 160;
        float v = (k < 150 && n < 450) ? U_iou[k * 450 + n] : 0.f;
        Uti[i2] = (short)f2bf(v);
    } else if (idx < nWt + nUi + nUf) {
        int i2 = idx - nWt - nUi; int n = i2 / 160, k = i2 % 160;
        float v = (k < 150 && n < 150) ? U_f[k * 150 + n] : 0.f;
        Utf[i2] = (short)f2bf(v);
    } else if (idx < nWt + nUi + nUf + WTN) {
        int c = idx - nWt - nUi - nUf;
        int k = c >> 2, g = c & 3;
        biasw[c] = (k < 150) ? (g < 3 ? b_iou[g * 150 + k] : b_f[k]) : 0.f;
    } else if (idx < nWt + nUi + nUf + WTN + HK) {
        int k = idx - (nWt + nUi + nUf + WTN);
        h_u[(long)ZROW * HK + k] = 0;
        c_u[(long)ZROW * HK + k] = 0.f;
    }
}

// ---------------- vocab projection via MFMA: proj[32000][600] bf16 ----------
// r13 structure with 256-row panels, grid 625 (125 rg x 5 cg) = ONE residency
// round at 3 blocks/CU capacity. Serial chunk chain per block: 10 -> 8.
// (r4-vs-r13 evidence: duration ~ chunks-executed x 4.3us; stage cost ~0.)
// Bijective XCD-chunked swizzle for nwg=625: q=78, r=1.
__global__ __launch_bounds__(256) void k_vproj(
    const float* __restrict__ emb, const short* __restrict__ Wt,
    const float* __restrict__ biasw, ushort* __restrict__ proj)
{
    __shared__ __align__(16) short As[2][32][328];
    const int tid = threadIdx.x;

    // bijective XCD-chunked swizzle: nwg=625, q=78, r=1
    const int bid = blockIdx.x;
    const int xcd = bid & 7, li = bid >> 3;
    const int wgid = (xcd == 0 ? 0 : 79 + (xcd - 1) * 78) + li;

    const int cg = wgid % 5;
    const int rg = wgid / 5;               // 0..124
    const int rowbase = rg * 256;

    const int w = tid >> 6, lane = tid & 63;
    const int m = lane & 15, kq = (lane >> 4) * 8;
    const int t0 = cg * 8 + w * 2;
    const int col0 = t0 * 16 + m;
    const int col1 = col0 + 16;

    short8 bq0[10], bq1[10];
    #pragma unroll
    for (int ks = 0; ks < 10; ks++) {
        bq0[ks] = *(const short8*)(Wt + (long)col0 * 320 + kq + ks * 32);
        bq1[ks] = *(const short8*)(Wt + (long)col1 * 320 + kq + ks * 32);
    }
    const float bias0 = biasw[col0];
    const float bias1 = biasw[col1];

    for (int i = tid; i < 2 * 32 * 5; i += 256) {
        int bz = i / 160, r2 = (i % 160) / 5, kk = (i % 5) * 4;
        *(short4*)&As[bz][r2][300 + kk] = make_short4(0, 0, 0, 0);
    }

    {
        const float4* src = (const float4*)emb + (long)rowbase * 75;
        for (int i = tid; i < 2400; i += 256) {
            int r = i / 75, k0 = (i % 75) * 4;
            float4 x = src[i];
            short4 sv;
            sv.x = (short)f2bf(x.x); sv.y = (short)f2bf(x.y);
            sv.z = (short)f2bf(x.z); sv.w = (short)f2bf(x.w);
            *(short4*)&As[0][r][k0] = sv;
        }
    }
    __syncthreads();

    for (int c = 0; c < 8; c++) {
        const int buf = c & 1;

        float4 x[10];
        if (c < 7) {
            const float4* src = (const float4*)emb + (long)(rowbase + (c + 1) * 32) * 75;
            #pragma unroll
            for (int j = 0; j < 10; j++) {
                int i = tid + j * 256;
                if (i < 2400) x[j] = src[i];
            }
        }

        floatx4 a00 = {0.f,0.f,0.f,0.f}, a01 = a00, a10 = a00, a11 = a00;
        #pragma unroll
        for (int ks = 0; ks < 10; ks++) {
            short8 a0 = *(const short8*)&As[buf][m][kq + ks * 32];
            short8 a1 = *(const short8*)&As[buf][16 + m][kq + ks * 32];
            a00 = __builtin_amdgcn_mfma_f32_16x16x32_bf16(a0, bq0[ks], a00, 0, 0, 0);
            a01 = __builtin_amdgcn_mfma_f32_16x16x32_bf16(a0, bq1[ks], a01, 0, 0, 0);
            a10 = __builtin_amdgcn_mfma_f32_16x16x32_bf16(a1, bq0[ks], a10, 0, 0, 0);
            a11 = __builtin_amdgcn_mfma_f32_16x16x32_bf16(a1, bq1[ks], a11, 0, 0, 0);
        }

        {
            int v0 = rowbase + c * 32;
            int rb = (lane >> 4) * 4;
            if (col0 < PROJC) {
                #pragma unroll
                for (int reg = 0; reg < 4; reg++) {
                    proj[(long)(v0 + rb + reg) * PROJC + col0]      = f2bf(a00[reg] + bias0);
                    proj[(long)(v0 + 16 + rb + reg) * PROJC + col0] = f2bf(a10[reg] + bias0);
                }
            }
            if (col1 < PROJC) {
                #pragma unroll
                for (int reg = 0; reg < 4; reg++) {
                    proj[(long)(v0 + rb + reg) * PROJC + col1]      = f2bf(a01[reg] + bias1);
                    proj[(long)(v0 + 16 + rb + reg) * PROJC + col1] = f2bf(a11[reg] + bias1);
                }
            }
        }

        if (c < 7) {
            #pragma unroll
            for (int j = 0; j < 10; j++) {
                int i = tid + j * 256;
                if (i < 2400) {
                    int r = i / 75, k0 = (i % 75) * 4;
                    short4 sv;
                    sv.x = (short)f2bf(x[j].x); sv.y = (short)f2bf(x[j].y);
                    sv.z = (short)f2bf(x[j].z); sv.w = (short)f2bf(x[j].w);
                    *(short4*)&As[buf ^ 1][r][k0] = sv;
                }
            }
        }
        __syncthreads();
    }
}

// ---------------- vocab leaf tables: rows 0..31999 of h_u/c_u ----------------
// Gate-interleaved proj: the 4 preactivations of k are ONE contiguous short4
// at pr + 4k -> a single fully-coalesced read stream.
__global__ __launch_bounds__(256) void k_vleaf(
    const ushort* __restrict__ proj, ushort* __restrict__ h_u, float* __restrict__ c_u)
{
    int idx = blockIdx.x * 256 + threadIdx.x;      // < 32000*20
    int v = idx / 20, k0 = (idx % 20) * 8;
    const ushort* pr = proj + (long)v * PROJC + 4 * k0;
    ushort hv[8]; float cvv[8];
    #pragma unroll
    for (int e = 0; e < 8; e++) {
        int k = k0 + e;
        if (k < Hh) {
            short4 q = *(const short4*)(pr + 4 * e);   // {i,o,u,f} of k
            float iv = sigf(bf2f((ushort)q.x));
            float ov = sigf(bf2f((ushort)q.y));
            float uv = tanhf_(bf2f((ushort)q.z));
            float cc = iv * uv;
            cvv[e] = cc;
            hv[e] = f2bf(ov * tanhf_(cc));
        } else { cvv[e] = 0.f; hv[e] = 0; }
    }
    *(int4*)(h_u + (long)v * HK + k0) = *(int4*)hv;
    *(float4*)(c_u + (long)v * HK + k0)     = make_float4(cvv[0], cvv[1], cvv[2], cvv[3]);
    *(float4*)(c_u + (long)v * HK + k0 + 4) = make_float4(cvv[4], cvv[5], cvv[6], cvv[7]);
}

// ---------------- level step (shared body): fused MFMA + gates --------------
// Round-5 measured structure. Gate-interleaved proj: the 4 preactivations of
// output col k are one aligned 8B short4 at pr + 4*col.
template<int CB>
__device__ __forceinline__ void level_step(
    int tA, int nT, int r0, int cb,
    const int* __restrict__ tq, const int* __restrict__ tp, const int* __restrict__ tn,
    const int* __restrict__ children, const ushort* __restrict__ proj,
    const short* __restrict__ Uti, const short* __restrict__ Utf,
    ushort* __restrict__ h_u, float* __restrict__ c_u,
    short (*As)[16][168], ushort (*idx_s)[16][4], ushort (*tok_s)[16])
{
    const int tid = threadIdx.x;

    if (tid < 64 * nT) {
        int tt = tid >> 6, q = tid & 63;
        int r = q >> 2, j = q & 3;
        int t = tA + tt;
        int rg = r0 + r, g = rg >> 7, b = rg & 127;
        const int* tok = (g == 0) ? tq : (g == 1 ? tp : tn);
        int ch = children[t * 4 + j];
        int idx;
        if (ch < 0)        idx = ZROW;
        else if (ch >= 64) idx = tok[b * Nn + ch];          // leaf: vocab row
        else               idx = Vv + rg * NINT + ch;       // internal row
        idx_s[tt][r][j] = (ushort)idx;
        if (j == 0) tok_s[tt][r] = (ushort)tok[b * Nn + t];
    }
    __syncthreads();

    // stage child h rows (bf16) + bf16 row-sum, all tt
    for (int i = tid; i < 320 * nT; i += 256) {
        int tt = i / 320, i2 = i % 320;
        int r = i2 / 20, k0 = (i2 % 20) * 8;
        int4 v0 = *(const int4*)(h_u + (long)idx_s[tt][r][0] * HK + k0);
        int4 v1 = *(const int4*)(h_u + (long)idx_s[tt][r][1] * HK + k0);
        int4 v2 = *(const int4*)(h_u + (long)idx_s[tt][r][2] * HK + k0);
        int4 v3 = *(const int4*)(h_u + (long)idx_s[tt][r][3] * HK + k0);
        *(int4*)&As[tt * 5 + 1][r][k0] = v0;
        *(int4*)&As[tt * 5 + 2][r][k0] = v1;
        *(int4*)&As[tt * 5 + 3][r][k0] = v2;
        *(int4*)&As[tt * 5 + 4][r][k0] = v3;
        ushort s[8];
        const ushort* p0 = (const ushort*)&v0; const ushort* p1 = (const ushort*)&v1;
        const ushort* p2 = (const ushort*)&v2; const ushort* p3 = (const ushort*)&v3;
        #pragma unroll
        for (int e = 0; e < 8; e++)
            s[e] = f2bf(bf2f(p0[e]) + bf2f(p1[e]) + bf2f(p2[e]) + bf2f(p3[e]));
        *(int4*)&As[tt * 5 + 0][r][k0] = *(int4*)s;
    }
    __syncthreads();

    const int w = tid >> 6, lane = tid & 63;
    const int m = lane & 15, kq = (lane >> 4) * 8;
    const int rbase = (lane >> 4) * 4;

    for (int nt = w + 4 * cb; nt < 10; nt += 4 * CB) {
        int col = nt * 16 + m;

        // B fragments hoisted: loaded once, reused for all tt
        short8 Bi[5], Bo[5], Bu[5], Bf[5];
        #pragma unroll
        for (int ks = 0; ks < 5; ks++) {
            Bi[ks] = *(const short8*)(Uti + (long)(col)       * HK + kq + ks * 32);
            Bo[ks] = *(const short8*)(Uti + (long)(150 + col) * HK + kq + ks * 32);
            Bu[ks] = *(const short8*)(Uti + (long)(300 + col) * HK + kq + ks * 32);
            Bf[ks] = *(const short8*)(Utf + (long)(col)       * HK + kq + ks * 32);
        }

        for (int tt = 0; tt < nT; ++tt) {
            int t = tA + tt;

            // prefetch epilogue operands BEFORE the MFMA cluster
            float pv0[4], pv1[4], pv2[4], pv3[4];
            float cu0[4], cu1[4], cu2[4], cu3[4];
            if (col < Hh) {
                #pragma unroll
                for (int reg = 0; reg < 4; reg++) {
                    const ushort* pr = proj + (long)tok_s[tt][rbase + reg] * PROJC;
                    short4 q4 = *(const short4*)(pr + 4 * col);   // {i,o,u,f} of col
                    pv0[reg] = bf2f((ushort)q4.x);
                    pv1[reg] = bf2f((ushort)q4.y);
                    pv2[reg] = bf2f((ushort)q4.z);
                    pv3[reg] = bf2f((ushort)q4.w);
                    cu0[reg] = c_u[(long)idx_s[tt][rbase + reg][0] * HK + col];
                    cu1[reg] = c_u[(long)idx_s[tt][rbase + reg][1] * HK + col];
                    cu2[reg] = c_u[(long)idx_s[tt][rbase + reg][2] * HK + col];
                    cu3[reg] = c_u[(long)idx_s[tt][rbase + reg][3] * HK + col];
                }
            }

            floatx4 ai = {0.f,0.f,0.f,0.f}, ao = ai, au = ai;
            floatx4 af0 = ai, af1 = ai, af2 = ai, af3 = ai;
            #pragma unroll
            for (int ks = 0; ks < 5; ks++) {
                short8 asum = *(const short8*)&As[tt * 5 + 0][m][kq + ks * 32];
                short8 ac0  = *(const short8*)&As[tt * 5 + 1][m][kq + ks * 32];
                short8 ac1  = *(const short8*)&As[tt * 5 + 2][m][kq + ks * 32];
                short8 ac2  = *(const short8*)&As[tt * 5 + 3][m][kq + ks * 32];
                short8 ac3  = *(const short8*)&As[tt * 5 + 4][m][kq + ks * 32];
                ai  = __builtin_amdgcn_mfma_f32_16x16x32_bf16(asum, Bi[ks], ai, 0, 0, 0);
                ao  = __builtin_amdgcn_mfma_f32_16x16x32_bf16(asum, Bo[ks], ao, 0, 0, 0);
                au  = __builtin_amdgcn_mfma_f32_16x16x32_bf16(asum, Bu[ks], au, 0, 0, 0);
                af0 = __builtin_amdgcn_mfma_f32_16x16x32_bf16(ac0,  Bf[ks], af0, 0, 0, 0);
                af1 = __builtin_amdgcn_mfma_f32_16x16x32_bf16(ac1,  Bf[ks], af1, 0, 0, 0);
                af2 = __builtin_amdgcn_mfma_f32_16x16x32_bf16(ac2,  Bf[ks], af2, 0, 0, 0);
                af3 = __builtin_amdgcn_mfma_f32_16x16x32_bf16(ac3,  Bf[ks], af3, 0, 0, 0);
            }

            if (col < Hh) {
                #pragma unroll
                for (int reg = 0; reg < 4; reg++) {
                    int rg = r0 + rbase + reg;
                    float iv = sigf(pv0[reg] + ai[reg]);
                    float ov = sigf(pv1[reg] + ao[reg]);
                    float uv = tanhf_(pv2[reg] + au[reg]);
                    float fpre = pv3[reg];
                    float cv = iv * uv;
                    cv = fmaf(sigf(fpre + af0[reg]), cu0[reg], cv);
                    cv = fmaf(sigf(fpre + af1[reg]), cu1[reg], cv);
                    cv = fmaf(sigf(fpre + af2[reg]), cu2[reg], cv);
                    cv = fmaf(sigf(fpre + af3[reg]), cu3[reg], cv);
                    long o = (long)(Vv + rg * NINT + t) * HK + col;
                    c_u[o] = cv;
                    h_u[o] = f2bf(ov * tanhf_(cv));
                }
            } else {
                #pragma unroll
                for (int reg = 0; reg < 4; reg++) {
                    long o = (long)(Vv + (r0 + rbase + reg) * NINT + t) * HK + col;
                    c_u[o] = 0.f; h_u[o] = 0;
                }
            }
        }
    }
}

// ---------------- internal level kernel ------------------------------------
// CB=1: one block per (chunk, row-group), all 10 col tiles (levels 1,2).
// CB=2: two blocks per (chunk, row-group), ~5 col tiles each -> per-block
// serial nt-chain halved (levels 3,4 — chain-bound).
template<int CB>
__global__ __launch_bounds__(256) void k_level(
    int t_base, int t_cnt,
    const int* __restrict__ tq, const int* __restrict__ tp, const int* __restrict__ tn,
    const int* __restrict__ children, const ushort* __restrict__ proj,
    const short* __restrict__ Uti, const short* __restrict__ Utf,
    ushort* __restrict__ h_u, float* __restrict__ c_u)
{
    __shared__ __align__(16) short As[10][16][168];   // [tt*5+seg][row][k]
    __shared__ ushort idx_s[2][16][4];
    __shared__ ushort tok_s[2][16];

    const int chunk = blockIdx.x / (24 * CB);
    const int rem   = blockIdx.x % (24 * CB);
    const int r0 = (rem / CB) * 16;
    const int cb = rem % CB;
    const int tA = t_base + chunk * 2;
    const int nT = min(2, t_base + t_cnt - tA);

    level_step<CB>(tA, nT, r0, cb, tq, tp, tn, children, proj, Uti, Utf,
                   h_u, c_u, As, idx_s, tok_s);
}

// ---------------- cosine + triplet loss ----------------
__global__ __launch_bounds__(64) void k_cos(const float* __restrict__ c_u, float* __restrict__ out)
{
    int b = blockIdx.x, tid = threadIdx.x;
    const float* qc = c_u + (long)(Vv + (0 * Bb + b) * NINT) * HK;
    const float* pc = c_u + (long)(Vv + (1 * Bb + b) * NINT) * HK;
    const float* nc = c_u + (long)(Vv + (2 * Bb + b) * NINT) * HK;
    float qp = 0, qn = 0, qq = 0, pp = 0, nn2 = 0;
    for (int k = tid; k < Hh; k += 64) {
        float qv = qc[k], pv = pc[k], nv = nc[k];
        qp += qv * pv; qn += qv * nv; qq += qv * qv; pp += pv * pv; nn2 += nv * nv;
    }
    #pragma unroll
    for (int off = 32; off > 0; off >>= 1) {
        qp += __shfl_down(qp, off, 64);
        qn += __shfl_down(qn, off, 64);
        qq += __shfl_down(qq, off, 64);
        pp += __shfl_down(pp, off, 64);
        nn2 += __shfl_down(nn2, off, 64);
    }
    if (tid == 0) {
        float a = qp / (sqrtf(qq * pp) + 1e-8f);
        float d = qn / (sqrtf(qq * nn2) + 1e-8f);
        out[b] = fmaxf(0.0f, 1.0f - a + d);
    }
}

extern "C" void kernel_launch(void* const* d_in, const int* in_sizes, int n_in,
                              void* d_out, int out_size, void* d_ws, size_t ws_size,
                              hipStream_t stream)
{
    const int*   tq       = (const int*)d_in[0];
    const int*   tp       = (const int*)d_in[1];
    const int*   tn       = (const int*)d_in[2];
    const int*   children = (const int*)d_in[3];
    const float* emb      = (const float*)d_in[4];
    const float* W_iou    = (const float*)d_in[5];
    const float* U_iou    = (const float*)d_in[6];
    const float* b_iou    = (const float*)d_in[7];
    const float* W_f      = (const float*)d_in[8];
    const float* U_f      = (const float*)d_in[9];
    const float* b_f      = (const float*)d_in[10];
    float* out = (float*)d_out;

    char* ws = (char*)d_ws;
    ushort* proj  = (ushort*)ws;                        // 32000*600*2          = 38,400,000
    ushort* h_u   = (ushort*)(ws + 38400000);           // 56577*160*2          = 18,104,640
    float*  c_u   = (float*)(ws + 56504640);            // 56577*160*4          = 36,209,280
    short*  Wt    = (short*)(ws + 92713920);            // 640*320*2            = 409,600
    short*  Uti   = (short*)(ws + 93123520);            // 464*160*2            = 148,480
    short*  Utf   = (short*)(ws + 93272000);            // 160*160*2            = 51,200
    float*  biasw = (float*)(ws + 93323200);            // 640*4                = 2,560

    k_prep<<<1194, 256, 0, stream>>>(W_iou, W_f, U_iou, U_f, b_iou, b_f,
                                     Wt, Uti, Utf, biasw, h_u, c_u);
    k_vproj<<<625, 256, 0, stream>>>(emb, Wt, biasw, proj);
    k_vleaf<<<2500, 256, 0, stream>>>(proj, h_u, c_u);
    // level 1: t=21..63 (22 chunks, last nT=1). 528 blocks @ 3/CU = 1 round.
    k_level<1><<<22 * 24, 256, 0, stream>>>(21, 43, tq, tp, tn, children, proj, Uti, Utf, h_u, c_u);
    // level 2: t=5..20
    k_level<1><<<8 * 24, 256, 0, stream>>>(5, 16, tq, tp, tn, children, proj, Uti, Utf, h_u, c_u);
    // level 3: t=1..4, col-split x2 (chain-bound: halve per-block nt loop)
    k_level<2><<<2 * 24 * 2, 256, 0, stream>>>(1, 4, tq, tp, tn, children, proj, Uti, Utf, h_u, c_u);
    // level 4: t=0, col-split x2
    k_level<2><<<1 * 24 * 2, 256, 0, stream>>>(0, 1, tq, tp, tn, children, proj, Uti, Utf, h_u, c_u);
    k_cos<<<Bb, 64, 0, stream>>>(c_u, out);
}

// Round 15
// 237.926 us; speedup vs baseline: 1.0095x; 1.0095x over previous
//
#include <hip/hip_runtime.h>
#include <hip/hip_bf16.h>

typedef short short8 __attribute__((ext_vector_type(8)));
typedef float floatx4 __attribute__((ext_vector_type(4)));
typedef unsigned short ushort;

#define Bb 128
#define Nn 256
#define Hh 150
#define HK 160        // padded col dim for h,c storage
#define Vv 32000
#define NROW 384      // 3 trees * B
#define PROJC 600
#define NINT 64       // internal nodes per tree (0..63)
#define ZROW (Vv + NROW * NINT)   // 56576: zero sentinel row (fits ushort)

#define WTN 640       // Wt padded col count (40 tiles of 16)

// Wt/proj COLUMN LAYOUT (gate-interleaved): col c = k*4 + g,
// g: 0=i, 1=o, 2=u, 3=f; k = 0..149 real, 150..159 zero pad.
// -> proj row holds {i,o,u,f} of output-k contiguously: one short4 at 4k.

__device__ __forceinline__ float sigf(float x) { return 1.0f / (1.0f + __expf(-x)); }
__device__ __forceinline__ float tanhf_(float x) { return 1.0f - 2.0f / (__expf(2.0f * x) + 1.0f); }
__device__ __forceinline__ float bf2f(ushort s) { union { float f; unsigned u; } v; v.u = ((unsigned)s) << 16; return v.f; }
__device__ __forceinline__ ushort f2bf(float f) { __hip_bfloat16 h = __float2bfloat16(f); return *(ushort*)&h; }

// ---------------- prep: weights -> bf16 B-operand layout + zero sentinel ----
// WRITE-contiguous orientation (r13 measured-best).
__global__ __launch_bounds__(256) void k_prep(
    const float* __restrict__ W_iou, const float* __restrict__ W_f,
    const float* __restrict__ U_iou, const float* __restrict__ U_f,
    const float* __restrict__ b_iou, const float* __restrict__ b_f,
    short* __restrict__ Wt, short* __restrict__ Uti, short* __restrict__ Utf,
    float* __restrict__ biasw, ushort* __restrict__ h_u, float* __restrict__ c_u)
{
    int idx = blockIdx.x * 256 + threadIdx.x;
    const int nWt = WTN * 320, nUi = 464 * 160, nUf = 160 * 160;
    if (idx < nWt) {
        int c = idx / 320, kk = idx % 320;   // c = out col (gate-interleaved), kk = E index
        int k = c >> 2, g = c & 3;
        float v = 0.f;
        if (kk < 300 && k < 150)
            v = (g < 3) ? W_iou[kk * 450 + g * 150 + k] : W_f[kk * 150 + k];
        Wt[idx] = (short)f2bf(v);
    } else if (idx < nWt + nUi) {
        int i2 = idx - nWt; int n = i2 / 160, k = i2 % 160;
        float v = (k < 150 && n < 450) ? U_iou[k * 450 + n] : 0.f;
        Uti[i2] = (short)f2bf(v);
    } else if (idx < nWt + nUi + nUf) {
        int i2 = idx - nWt - nUi; int n = i2 / 160, k = i2 % 160;
        float v = (k < 150 && n < 150) ? U_f[k * 150 + n] : 0.f;
        Utf[i2] = (short)f2bf(v);
    } else if (idx < nWt + nUi + nUf + WTN) {
        int c = idx - nWt - nUi - nUf;
        int k = c >> 2, g = c & 3;
        biasw[c] = (k < 150) ? (g < 3 ? b_iou[g * 150 + k] : b_f[k]) : 0.f;
    } else if (idx < nWt + nUi + nUf + WTN + HK) {
        int k = idx - (nWt + nUi + nUf + WTN);
        h_u[(long)ZROW * HK + k] = 0;
        c_u[(long)ZROW * HK + k] = 0.f;
    }
}

// ---------------- vocab projection via MFMA: proj[32000][600] bf16 ----------
// r13 measured-best (43.4 us, five-times reproduced): column-stationary,
// 2 tiles/wave, 320-row panels, grid 500 (2 blocks/CU uniform — grid<=512 is
// the balance regime; r14's 625 hit 3-block straggler CUs, +16%), dual-buffer
// LDS, XCD-chunked swizzle.
__global__ __launch_bounds__(256) void k_vproj(
    const float* __restrict__ emb, const short* __restrict__ Wt,
    const float* __restrict__ biasw, ushort* __restrict__ proj)
{
    __shared__ __align__(16) short As[2][32][328];
    const int tid = threadIdx.x;

    // bijective XCD-chunked swizzle: nwg=500, q=62, r=4
    const int bid = blockIdx.x;
    const int xcd = bid & 7, li = bid >> 3;
    const int wgid = (xcd < 4 ? xcd * 63 : 252 + (xcd - 4) * 62) + li;

    const int cg = wgid % 5;
    const int rg = wgid / 5;
    const int rowbase = rg * 320;

    const int w = tid >> 6, lane = tid & 63;
    const int m = lane & 15, kq = (lane >> 4) * 8;
    const int t0 = cg * 8 + w * 2;
    const int col0 = t0 * 16 + m;
    const int col1 = col0 + 16;

    short8 bq0[10], bq1[10];
    #pragma unroll
    for (int ks = 0; ks < 10; ks++) {
        bq0[ks] = *(const short8*)(Wt + (long)col0 * 320 + kq + ks * 32);
        bq1[ks] = *(const short8*)(Wt + (long)col1 * 320 + kq + ks * 32);
    }
    const float bias0 = biasw[col0];
    const float bias1 = biasw[col1];

    for (int i = tid; i < 2 * 32 * 5; i += 256) {
        int bz = i / 160, r2 = (i % 160) / 5, kk = (i % 5) * 4;
        *(short4*)&As[bz][r2][300 + kk] = make_short4(0, 0, 0, 0);
    }

    {
        const float4* src = (const float4*)emb + (long)rowbase * 75;
        for (int i = tid; i < 2400; i += 256) {
            int r = i / 75, k0 = (i % 75) * 4;
            float4 x = src[i];
            short4 sv;
            sv.x = (short)f2bf(x.x); sv.y = (short)f2bf(x.y);
            sv.z = (short)f2bf(x.z); sv.w = (short)f2bf(x.w);
            *(short4*)&As[0][r][k0] = sv;
        }
    }
    __syncthreads();

    for (int c = 0; c < 10; c++) {
        const int buf = c & 1;

        float4 x[10];
        if (c < 9) {
            const float4* src = (const float4*)emb + (long)(rowbase + (c + 1) * 32) * 75;
            #pragma unroll
            for (int j = 0; j < 10; j++) {
                int i = tid + j * 256;
                if (i < 2400) x[j] = src[i];
            }
        }

        floatx4 a00 = {0.f,0.f,0.f,0.f}, a01 = a00, a10 = a00, a11 = a00;
        #pragma unroll
        for (int ks = 0; ks < 10; ks++) {
            short8 a0 = *(const short8*)&As[buf][m][kq + ks * 32];
            short8 a1 = *(const short8*)&As[buf][16 + m][kq + ks * 32];
            a00 = __builtin_amdgcn_mfma_f32_16x16x32_bf16(a0, bq0[ks], a00, 0, 0, 0);
            a01 = __builtin_amdgcn_mfma_f32_16x16x32_bf16(a0, bq1[ks], a01, 0, 0, 0);
            a10 = __builtin_amdgcn_mfma_f32_16x16x32_bf16(a1, bq0[ks], a10, 0, 0, 0);
            a11 = __builtin_amdgcn_mfma_f32_16x16x32_bf16(a1, bq1[ks], a11, 0, 0, 0);
        }

        {
            int v0 = rowbase + c * 32;
            int rb = (lane >> 4) * 4;
            if (col0 < PROJC) {
                #pragma unroll
                for (int reg = 0; reg < 4; reg++) {
                    proj[(long)(v0 + rb + reg) * PROJC + col0]      = f2bf(a00[reg] + bias0);
                    proj[(long)(v0 + 16 + rb + reg) * PROJC + col0] = f2bf(a10[reg] + bias0);
                }
            }
            if (col1 < PROJC) {
                #pragma unroll
                for (int reg = 0; reg < 4; reg++) {
                    proj[(long)(v0 + rb + reg) * PROJC + col1]      = f2bf(a01[reg] + bias1);
                    proj[(long)(v0 + 16 + rb + reg) * PROJC + col1] = f2bf(a11[reg] + bias1);
                }
            }
        }

        if (c < 9) {
            #pragma unroll
            for (int j = 0; j < 10; j++) {
                int i = tid + j * 256;
                if (i < 2400) {
                    int r = i / 75, k0 = (i % 75) * 4;
                    short4 sv;
                    sv.x = (short)f2bf(x[j].x); sv.y = (short)f2bf(x[j].y);
                    sv.z = (short)f2bf(x[j].z); sv.w = (short)f2bf(x[j].w);
                    *(short4*)&As[buf ^ 1][r][k0] = sv;
                }
            }
        }
        __syncthreads();
    }
}

// ---------------- vocab leaf tables: rows 0..31999 of h_u/c_u ----------------
// Gate-interleaved proj: the 4 preactivations of k are ONE contiguous short4
// at pr + 4k -> a single fully-coalesced read stream.
__global__ __launch_bounds__(256) void k_vleaf(
    const ushort* __restrict__ proj, ushort* __restrict__ h_u, float* __restrict__ c_u)
{
    int idx = blockIdx.x * 256 + threadIdx.x;      // < 32000*20
    int v = idx / 20, k0 = (idx % 20) * 8;
    const ushort* pr = proj + (long)v * PROJC + 4 * k0;
    ushort hv[8]; float cvv[8];
    #pragma unroll
    for (int e = 0; e < 8; e++) {
        int k = k0 + e;
        if (k < Hh) {
            short4 q = *(const short4*)(pr + 4 * e);   // {i,o,u,f} of k
            float iv = sigf(bf2f((ushort)q.x));
            float ov = sigf(bf2f((ushort)q.y));
            float uv = tanhf_(bf2f((ushort)q.z));
            float cc = iv * uv;
            cvv[e] = cc;
            hv[e] = f2bf(ov * tanhf_(cc));
        } else { cvv[e] = 0.f; hv[e] = 0; }
    }
    *(int4*)(h_u + (long)v * HK + k0) = *(int4*)hv;
    *(float4*)(c_u + (long)v * HK + k0)     = make_float4(cvv[0], cvv[1], cvv[2], cvv[3]);
    *(float4*)(c_u + (long)v * HK + k0 + 4) = make_float4(cvv[4], cvv[5], cvv[6], cvv[7]);
}

// ---------------- level step (shared body): fused MFMA + gates --------------
// Round-5 measured structure. Gate-interleaved proj: the 4 preactivations of
// output col k are one aligned 8B short4 at pr + 4*col.
template<int CB>
__device__ __forceinline__ void level_step(
    int tA, int nT, int r0, int cb,
    const int* __restrict__ tq, const int* __restrict__ tp, const int* __restrict__ tn,
    const int* __restrict__ children, const ushort* __restrict__ proj,
    const short* __restrict__ Uti, const short* __restrict__ Utf,
    ushort* __restrict__ h_u, float* __restrict__ c_u,
    short (*As)[16][168], ushort (*idx_s)[16][4], ushort (*tok_s)[16])
{
    const int tid = threadIdx.x;

    if (tid < 64 * nT) {
        int tt = tid >> 6, q = tid & 63;
        int r = q >> 2, j = q & 3;
        int t = tA + tt;
        int rg = r0 + r, g = rg >> 7, b = rg & 127;
        const int* tok = (g == 0) ? tq : (g == 1 ? tp : tn);
        int ch = children[t * 4 + j];
        int idx;
        if (ch < 0)        idx = ZROW;
        else if (ch >= 64) idx = tok[b * Nn + ch];          // leaf: vocab row
        else               idx = Vv + rg * NINT + ch;       // internal row
        idx_s[tt][r][j] = (ushort)idx;
        if (j == 0) tok_s[tt][r] = (ushort)tok[b * Nn + t];
    }
    __syncthreads();

    // stage child h rows (bf16) + bf16 row-sum, all tt
    for (int i = tid; i < 320 * nT; i += 256) {
        int tt = i / 320, i2 = i % 320;
        int r = i2 / 20, k0 = (i2 % 20) * 8;
        int4 v0 = *(const int4*)(h_u + (long)idx_s[tt][r][0] * HK + k0);
        int4 v1 = *(const int4*)(h_u + (long)idx_s[tt][r][1] * HK + k0);
        int4 v2 = *(const int4*)(h_u + (long)idx_s[tt][r][2] * HK + k0);
        int4 v3 = *(const int4*)(h_u + (long)idx_s[tt][r][3] * HK + k0);
        *(int4*)&As[tt * 5 + 1][r][k0] = v0;
        *(int4*)&As[tt * 5 + 2][r][k0] = v1;
        *(int4*)&As[tt * 5 + 3][r][k0] = v2;
        *(int4*)&As[tt * 5 + 4][r][k0] = v3;
        ushort s[8];
        const ushort* p0 = (const ushort*)&v0; const ushort* p1 = (const ushort*)&v1;
        const ushort* p2 = (const ushort*)&v2; const ushort* p3 = (const ushort*)&v3;
        #pragma unroll
        for (int e = 0; e < 8; e++)
            s[e] = f2bf(bf2f(p0[e]) + bf2f(p1[e]) + bf2f(p2[e]) + bf2f(p3[e]));
        *(int4*)&As[tt * 5 + 0][r][k0] = *(int4*)s;
    }
    __syncthreads();

    const int w = tid >> 6, lane = tid & 63;
    const int m = lane & 15, kq = (lane >> 4) * 8;
    const int rbase = (lane >> 4) * 4;

    for (int nt = w + 4 * cb; nt < 10; nt += 4 * CB) {
        int col = nt * 16 + m;

        // B fragments hoisted: loaded once, reused for all tt
        short8 Bi[5], Bo[5], Bu[5], Bf[5];
        #pragma unroll
        for (int ks = 0; ks < 5; ks++) {
            Bi[ks] = *(const short8*)(Uti + (long)(col)       * HK + kq + ks * 32);
            Bo[ks] = *(const short8*)(Uti + (long)(150 + col) * HK + kq + ks * 32);
            Bu[ks] = *(const short8*)(Uti + (long)(300 + col) * HK + kq + ks * 32);
            Bf[ks] = *(const short8*)(Utf + (long)(col)       * HK + kq + ks * 32);
        }

        for (int tt = 0; tt < nT; ++tt) {
            int t = tA + tt;

            // prefetch epilogue operands BEFORE the MFMA cluster
            float pv0[4], pv1[4], pv2[4], pv3[4];
            float cu0[4], cu1[4], cu2[4], cu3[4];
            if (col < Hh) {
                #pragma unroll
                for (int reg = 0; reg < 4; reg++) {
                    const ushort* pr = proj + (long)tok_s[tt][rbase + reg] * PROJC;
                    short4 q4 = *(const short4*)(pr + 4 * col);   // {i,o,u,f} of col
                    pv0[reg] = bf2f((ushort)q4.x);
                    pv1[reg] = bf2f((ushort)q4.y);
                    pv2[reg] = bf2f((ushort)q4.z);
                    pv3[reg] = bf2f((ushort)q4.w);
                    cu0[reg] = c_u[(long)idx_s[tt][rbase + reg][0] * HK + col];
                    cu1[reg] = c_u[(long)idx_s[tt][rbase + reg][1] * HK + col];
                    cu2[reg] = c_u[(long)idx_s[tt][rbase + reg][2] * HK + col];
                    cu3[reg] = c_u[(long)idx_s[tt][rbase + reg][3] * HK + col];
                }
            }

            floatx4 ai = {0.f,0.f,0.f,0.f}, ao = ai, au = ai;
            floatx4 af0 = ai, af1 = ai, af2 = ai, af3 = ai;
            #pragma unroll
            for (int ks = 0; ks < 5; ks++) {
                short8 asum = *(const short8*)&As[tt * 5 + 0][m][kq + ks * 32];
                short8 ac0  = *(const short8*)&As[tt * 5 + 1][m][kq + ks * 32];
                short8 ac1  = *(const short8*)&As[tt * 5 + 2][m][kq + ks * 32];
                short8 ac2  = *(const short8*)&As[tt * 5 + 3][m][kq + ks * 32];
                short8 ac3  = *(const short8*)&As[tt * 5 + 4][m][kq + ks * 32];
                ai  = __builtin_amdgcn_mfma_f32_16x16x32_bf16(asum, Bi[ks], ai, 0, 0, 0);
                ao  = __builtin_amdgcn_mfma_f32_16x16x32_bf16(asum, Bo[ks], ao, 0, 0, 0);
                au  = __builtin_amdgcn_mfma_f32_16x16x32_bf16(asum, Bu[ks], au, 0, 0, 0);
                af0 = __builtin_amdgcn_mfma_f32_16x16x32_bf16(ac0,  Bf[ks], af0, 0, 0, 0);
                af1 = __builtin_amdgcn_mfma_f32_16x16x32_bf16(ac1,  Bf[ks], af1, 0, 0, 0);
                af2 = __builtin_amdgcn_mfma_f32_16x16x32_bf16(ac2,  Bf[ks], af2, 0, 0, 0);
                af3 = __builtin_amdgcn_mfma_f32_16x16x32_bf16(ac3,  Bf[ks], af3, 0, 0, 0);
            }

            if (col < Hh) {
                #pragma unroll
                for (int reg = 0; reg < 4; reg++) {
                    int rg = r0 + rbase + reg;
                    float iv = sigf(pv0[reg] + ai[reg]);
                    float ov = sigf(pv1[reg] + ao[reg]);
                    float uv = tanhf_(pv2[reg] + au[reg]);
                    float fpre = pv3[reg];
                    float cv = iv * uv;
                    cv = fmaf(sigf(fpre + af0[reg]), cu0[reg], cv);
                    cv = fmaf(sigf(fpre + af1[reg]), cu1[reg], cv);
                    cv = fmaf(sigf(fpre + af2[reg]), cu2[reg], cv);
                    cv = fmaf(sigf(fpre + af3[reg]), cu3[reg], cv);
                    long o = (long)(Vv + rg * NINT + t) * HK + col;
                    c_u[o] = cv;
                    h_u[o] = f2bf(ov * tanhf_(cv));
                }
            } else {
                #pragma unroll
                for (int reg = 0; reg < 4; reg++) {
                    long o = (long)(Vv + (r0 + rbase + reg) * NINT + t) * HK + col;
                    c_u[o] = 0.f; h_u[o] = 0;
                }
            }
        }
    }
}

// ---------------- internal level kernel ------------------------------------
// CB=1: one block per (chunk, row-group), all 10 col tiles (level 1; CB=2
// would need 1056 blocks > 768 residency capacity).
// CB=2: two blocks per (chunk, row-group), ~5 col tiles each -> per-block
// serial nt-chain halved (levels 2,3,4 — chain-bound, grids fit 1 round).
template<int CB>
__global__ __launch_bounds__(256) void k_level(
    int t_base, int t_cnt,
    const int* __restrict__ tq, const int* __restrict__ tp, const int* __restrict__ tn,
    const int* __restrict__ children, const ushort* __restrict__ proj,
    const short* __restrict__ Uti, const short* __restrict__ Utf,
    ushort* __restrict__ h_u, float* __restrict__ c_u)
{
    __shared__ __align__(16) short As[10][16][168];   // [tt*5+seg][row][k]
    __shared__ ushort idx_s[2][16][4];
    __shared__ ushort tok_s[2][16];

    const int chunk = blockIdx.x / (24 * CB);
    const int rem   = blockIdx.x % (24 * CB);
    const int r0 = (rem / CB) * 16;
    const int cb = rem % CB;
    const int tA = t_base + chunk * 2;
    const int nT = min(2, t_base + t_cnt - tA);

    level_step<CB>(tA, nT, r0, cb, tq, tp, tn, children, proj, Uti, Utf,
                   h_u, c_u, As, idx_s, tok_s);
}

// ---------------- cosine + triplet loss ----------------
__global__ __launch_bounds__(64) void k_cos(const float* __restrict__ c_u, float* __restrict__ out)
{
    int b = blockIdx.x, tid = threadIdx.x;
    const float* qc = c_u + (long)(Vv + (0 * Bb + b) * NINT) * HK;
    const float* pc = c_u + (long)(Vv + (1 * Bb + b) * NINT) * HK;
    const float* nc = c_u + (long)(Vv + (2 * Bb + b) * NINT) * HK;
    float qp = 0, qn = 0, qq = 0, pp = 0, nn2 = 0;
    for (int k = tid; k < Hh; k += 64) {
        float qv = qc[k], pv = pc[k], nv = nc[k];
        qp += qv * pv; qn += qv * nv; qq += qv * qv; pp += pv * pv; nn2 += nv * nv;
    }
    #pragma unroll
    for (int off = 32; off > 0; off >>= 1) {
        qp += __shfl_down(qp, off, 64);
        qn += __shfl_down(qn, off, 64);
        qq += __shfl_down(qq, off, 64);
        pp += __shfl_down(pp, off, 64);
        nn2 += __shfl_down(nn2, off, 64);
    }
    if (tid == 0) {
        float a = qp / (sqrtf(qq * pp) + 1e-8f);
        float d = qn / (sqrtf(qq * nn2) + 1e-8f);
        out[b] = fmaxf(0.0f, 1.0f - a + d);
    }
}

extern "C" void kernel_launch(void* const* d_in, const int* in_sizes, int n_in,
                              void* d_out, int out_size, void* d_ws, size_t ws_size,
                              hipStream_t stream)
{
    const int*   tq       = (const int*)d_in[0];
    const int*   tp       = (const int*)d_in[1];
    const int*   tn       = (const int*)d_in[2];
    const int*   children = (const int*)d_in[3];
    const float* emb      = (const float*)d_in[4];
    const float* W_iou    = (const float*)d_in[5];
    const float* U_iou    = (const float*)d_in[6];
    const float* b_iou    = (const float*)d_in[7];
    const float* W_f      = (const float*)d_in[8];
    const float* U_f      = (const float*)d_in[9];
    const float* b_f      = (const float*)d_in[10];
    float* out = (float*)d_out;

    char* ws = (char*)d_ws;
    ushort* proj  = (ushort*)ws;                        // 32000*600*2          = 38,400,000
    ushort* h_u   = (ushort*)(ws + 38400000);           // 56577*160*2          = 18,104,640
    float*  c_u   = (float*)(ws + 56504640);            // 56577*160*4          = 36,209,280
    short*  Wt    = (short*)(ws + 92713920);            // 640*320*2            = 409,600
    short*  Uti   = (short*)(ws + 93123520);            // 464*160*2            = 148,480
    short*  Utf   = (short*)(ws + 93272000);            // 160*160*2            = 51,200
    float*  biasw = (float*)(ws + 93323200);            // 640*4                = 2,560

    k_prep<<<1194, 256, 0, stream>>>(W_iou, W_f, U_iou, U_f, b_iou, b_f,
                                     Wt, Uti, Utf, biasw, h_u, c_u);
    k_vproj<<<500, 256, 0, stream>>>(emb, Wt, biasw, proj);
    k_vleaf<<<2500, 256, 0, stream>>>(proj, h_u, c_u);
    // level 1: t=21..63 (22 chunks, last nT=1). 528 blocks @ 3/CU = 1 round.
    k_level<1><<<22 * 24, 256, 0, stream>>>(21, 43, tq, tp, tn, children, proj, Uti, Utf, h_u, c_u);
    // level 2: t=5..20, col-split x2 (384 blocks, 1 round, chain halved)
    k_level<2><<<8 * 24 * 2, 256, 0, stream>>>(5, 16, tq, tp, tn, children, proj, Uti, Utf, h_u, c_u);
    // level 3: t=1..4, col-split x2
    k_level<2><<<2 * 24 * 2, 256, 0, stream>>>(1, 4, tq, tp, tn, children, proj, Uti, Utf, h_u, c_u);
    // level 4: t=0, col-split x2
    k_level<2><<<1 * 24 * 2, 256, 0, stream>>>(0, 1, tq, tp, tn, children, proj, Uti, Utf, h_u, c_u);
    k_cos<<<Bb, 64, 0, stream>>>(c_u, out);
}